// Round 8
// baseline (953.794 us; speedup 1.0000x reference)
//
#include <hip/hip_runtime.h>
#include <hip/hip_bf16.h>

#define BATCH 2
#define SEQ   2048
#define HIDN  1024
#define NH    16
#define HD    64

typedef __attribute__((ext_vector_type(8))) short short8;
typedef __attribute__((ext_vector_type(4))) float floatx4;
typedef __attribute__((ext_vector_type(8))) unsigned short ushort8;
typedef __attribute__((ext_vector_type(4))) unsigned short ushort4v;

__device__ __forceinline__ unsigned short f2bf(float f) {
    union { float f; unsigned int u; } v; v.f = f;
    unsigned int u = v.u;
    u += 0x7fffu + ((u >> 16) & 1u);   // round-to-nearest-even
    return (unsigned short)(u >> 16);
}

__device__ __forceinline__ ushort8 pack16(float4 f0, float4 f1) {
    ushort8 r;
    r[0] = f2bf(f0.x); r[1] = f2bf(f0.y); r[2] = f2bf(f0.z); r[3] = f2bf(f0.w);
    r[4] = f2bf(f1.x); r[5] = f2bf(f1.y); r[6] = f2bf(f1.z); r[7] = f2bf(f1.w);
    return r;
}

// ---------------------------------------------------------------------------
// Kernel A: fused QKV projection.  y = x @ w^T + b.
// Writes bf16 [B][H][S][D]; q is pre-scaled by softplus(scaling[d])*LOG2E^2/8
// so that attention can use exp2 directly:
//   reference logit x = raw*softplus*LOG2E/8;  prob = e^x
//   our s = raw*softplus*LOG2E^2/8 = x*LOG2E;  2^s = e^x   (exact refactor)
// 128x128 tile, 4 waves, 16x16x32 bf16 MFMA.
// ---------------------------------------------------------------------------
__global__ __launch_bounds__(256) void qkv_kernel(
    const float* __restrict__ x,
    const float* __restrict__ qw, const float* __restrict__ qbias,
    const float* __restrict__ kw, const float* __restrict__ kbias,
    const float* __restrict__ vw, const float* __restrict__ vbias,
    const float* __restrict__ scaling,
    unsigned short* __restrict__ qo,
    unsigned short* __restrict__ ko,
    unsigned short* __restrict__ vo)
{
    const int z = blockIdx.z;
    const float* w    = (z == 0) ? qw : (z == 1) ? kw : vw;
    const float* bias = (z == 0) ? qbias : (z == 1) ? kbias : vbias;
    unsigned short* dst = (z == 0) ? qo : (z == 1) ? ko : vo;

    const int n0 = blockIdx.x * 128;
    const int m0 = blockIdx.y * 128;
    const int tid  = threadIdx.x;
    const int lane = tid & 63;
    const int wv   = tid >> 6;
    const int nidx = lane & 15;
    const int quad = lane >> 4;

    __shared__ unsigned short As[128][40];  // +8 pad, rows stay 16B aligned
    __shared__ unsigned short Bs[128][40];

    floatx4 acc[2][8];
#pragma unroll
    for (int rt = 0; rt < 2; rt++)
#pragma unroll
        for (int ct = 0; ct < 8; ct++) acc[rt][ct] = (floatx4)0.0f;

    const int srow = tid >> 1;          // 0..127
    const int scol = (tid & 1) * 16;    // 0 or 16 (floats)

    for (int k0 = 0; k0 < HIDN; k0 += 32) {
        __syncthreads();
        {
            const float4* g = (const float4*)(x + (size_t)(m0 + srow) * HIDN + k0 + scol);
            float4 f0 = g[0], f1 = g[1], f2 = g[2], f3 = g[3];
            *(ushort8*)&As[srow][scol]     = pack16(f0, f1);
            *(ushort8*)&As[srow][scol + 8] = pack16(f2, f3);
        }
        {
            const float4* g = (const float4*)(w + (size_t)(n0 + srow) * HIDN + k0 + scol);
            float4 f0 = g[0], f1 = g[1], f2 = g[2], f3 = g[3];
            *(ushort8*)&Bs[srow][scol]     = pack16(f0, f1);
            *(ushort8*)&Bs[srow][scol + 8] = pack16(f2, f3);
        }
        __syncthreads();

        short8 a[2], bb[8];
#pragma unroll
        for (int rt = 0; rt < 2; rt++)
            a[rt] = *(const short8*)&As[wv * 32 + rt * 16 + nidx][quad * 8];
#pragma unroll
        for (int ct = 0; ct < 8; ct++)
            bb[ct] = *(const short8*)&Bs[ct * 16 + nidx][quad * 8];
#pragma unroll
        for (int rt = 0; rt < 2; rt++)
#pragma unroll
            for (int ct = 0; ct < 8; ct++)
                acc[rt][ct] = __builtin_amdgcn_mfma_f32_16x16x32_bf16(a[rt], bb[ct], acc[rt][ct], 0, 0, 0);
    }

#pragma unroll
    for (int ct = 0; ct < 8; ct++) {
        int col = n0 + ct * 16 + nidx;
        float bcol = bias[col];
        float mult = 1.0f;
        if (z == 0) {
            float sc = scaling[col & (HD - 1)];
            // softplus(sc) * LOG2E^2 / 8  (LOG2E^2 = 2.0813689)
            mult = __logf(1.0f + __expf(sc)) * 0.26017112f;
        }
#pragma unroll
        for (int rt = 0; rt < 2; rt++) {
#pragma unroll
            for (int rg = 0; rg < 4; rg++) {
                int row = m0 + wv * 32 + rt * 16 + quad * 4 + rg;  // C/D: col=lane&15, row=quad*4+reg
                float val = (acc[rt][ct][rg] + bcol) * mult;
                int b_ = row >> 11, s_ = row & (SEQ - 1);
                int h_ = col >> 6,  d_ = col & (HD - 1);
                dst[((size_t)(b_ * NH + h_) * SEQ + s_) * HD + d_] = f2bf(val);
            }
        }
    }
}

// ---------------------------------------------------------------------------
// Kernel B: causal attention, SINGLE PASS.  Each block serially processes the
// complementary q-tile pair {bx, 31-bx} -> uniform 33 k-tiles per block.
//
// QK^T operand-swapped: mfma(A=K-subtile, B=Q-rows) -> D-fragment is S^T:
// col(lane&15)=q-row, row(quad*4+rg)=k-col.  Each lane owns 4 CONSECUTIVE
// k-columns of one q-row.  Per k-tile: stage-prefetch V^T (double-buffered,
// ONE barrier), K frags direct from global (L2-resident), 8 QK^T MFMA,
// e=2^s (q pre-scaled so 2^s == e^logit), write UNNORMALIZED e to attn
// (float4 NT), accumulate psum, Ps bf16 -> 8 PV MFMA.  After the loop:
// invl = 1/sum, normalize ctx, store invl per row; a separate rescale
// kernel multiplies the attn lower triangle by invl (upper is exact 0).
// ---------------------------------------------------------------------------
__global__ __launch_bounds__(256) void attn_kernel(
    const unsigned short* __restrict__ q,
    const unsigned short* __restrict__ k,
    const unsigned short* __restrict__ v,
    float* __restrict__ attn,
    unsigned short* __restrict__ ctx,
    float* __restrict__ invl_g)
{
    const int h  = blockIdx.y;
    const int b  = blockIdx.z;
    const int tid  = threadIdx.x;
    const int lane = tid & 63;
    const int wv   = tid >> 6;
    const int nidx = lane & 15;
    const int quad = lane >> 4;

    const unsigned short* qg = q + (size_t)((b * NH + h) * SEQ) * HD;
    const unsigned short* kg = k + (size_t)((b * NH + h) * SEQ) * HD;
    const unsigned short* vg = v + (size_t)((b * NH + h) * SEQ) * HD;
    float* ag = attn + (size_t)(b * NH + h) * SEQ * SEQ;
    float* ig = invl_g + (size_t)(b * NH + h) * SEQ;

    __shared__ unsigned short Vs[2][64][72];   // V^T double buffer: [d][key]
    __shared__ unsigned short Ps[64][72];

    const int srow = tid >> 2;   // 0..63
    const int sseg = tid & 3;    // 0..3
    const int qrowl = wv * 16 + nidx;          // this lane's q-row (local)
    const int crow0 = wv * 16 + quad * 4;      // PV C-frag first row (local)

    for (int rep = 0; rep < 2; rep++) {
        const int qt = rep ? (31 - (int)blockIdx.x) : (int)blockIdx.x;
        __syncthreads();   // rep>0: previous rep's PV reads of Vs done

        // Q rows: loop-invariant B-operand of swapped QK^T, direct from global
        const unsigned short* qrow = qg + (size_t)(qt * 64 + qrowl) * HD;
        const short8 qb0 = *(const short8*)(qrow + quad * 8);
        const short8 qb1 = *(const short8*)(qrow + 32 + quad * 8);
        const int qrowg = qt * 64 + qrowl;     // global q-row

        float psum = 0.0f;
        floatx4 oacc[4];
#pragma unroll
        for (int ct = 0; ct < 4; ct++) oacc[ct] = (floatx4)0.0f;

        {   // prologue: stage V^T tile 0 into buffer 0
            const uint4* g = (const uint4*)(vg + (size_t)(srow) * HD);
            uint4 u0 = g[sseg], u1 = g[sseg + 4];
            union { uint4 u; unsigned short s[8]; } w0, w1;
            w0.u = u0; w1.u = u1;
#pragma unroll
            for (int j = 0; j < 8; j++) Vs[0][sseg * 8 + j][srow]      = w0.s[j];
#pragma unroll
            for (int j = 0; j < 8; j++) Vs[0][sseg * 8 + 32 + j][srow] = w1.s[j];
        }

        for (int kt = 0; kt <= qt; kt++) {
            __syncthreads();   // staging of Vs[kt&1] (prev iter / prologue) visible
            // prefetch-stage next V tile into the other buffer (overlaps compute)
            if (kt < qt) {
                const uint4* g = (const uint4*)(vg + (size_t)((kt + 1) * 64 + srow) * HD);
                uint4 u0 = g[sseg], u1 = g[sseg + 4];
                union { uint4 u; unsigned short s[8]; } w0, w1;
                w0.u = u0; w1.u = u1;
                const int nb = (kt + 1) & 1;
#pragma unroll
                for (int j = 0; j < 8; j++) Vs[nb][sseg * 8 + j][srow]      = w0.s[j];
#pragma unroll
                for (int j = 0; j < 8; j++) Vs[nb][sseg * 8 + 32 + j][srow] = w1.s[j];
            }

            const unsigned short* kbase = kg + (size_t)(kt * 64) * HD;
            const bool diag = (kt == qt);
            const int cb = kt & 1;
#pragma unroll
            for (int ct = 0; ct < 4; ct++) {
                const unsigned short* krow = kbase + (ct * 16 + nidx) * HD;
                short8 ak0 = *(const short8*)(krow + quad * 8);
                short8 ak1 = *(const short8*)(krow + 32 + quad * 8);
                floatx4 sacc = (floatx4)0.0f;
                __builtin_amdgcn_s_setprio(1);
                sacc = __builtin_amdgcn_mfma_f32_16x16x32_bf16(ak0, qb0, sacc, 0, 0, 0);
                sacc = __builtin_amdgcn_mfma_f32_16x16x32_bf16(ak1, qb1, sacc, 0, 0, 0);
                __builtin_amdgcn_s_setprio(0);
                const int kcol0 = kt * 64 + ct * 16 + quad * 4;
                floatx4 av;
                ushort4v pb;
#pragma unroll
                for (int rg = 0; rg < 4; rg++) {
                    float e = exp2f(sacc[rg]);     // == e^logit (prescale has LOG2E^2)
                    if (diag && kcol0 + rg > qrowg) e = 0.0f;
                    av[rg] = e;                    // UNNORMALIZED; rescale later
                    pb[rg] = f2bf(e);              // unnormalized P for PV
                    psum += e;
                }
                __builtin_nontemporal_store(av, (floatx4*)&ag[(size_t)qrowg * SEQ + kcol0]);
                *(ushort4v*)&Ps[qrowl][ct * 16 + quad * 4] = pb;      // 8B ds_write
            }
            // No barrier: Ps rows [wv*16, wv*16+16) are written and read by
            // the SAME wave; compiler inserts the lgkmcnt wait.

            // PV: ctx[q][d] += P~[q][key] * V[key][d]
            __builtin_amdgcn_s_setprio(1);
#pragma unroll
            for (int ki = 0; ki < 2; ki++) {
                short8 pa = *(const short8*)&Ps[qrowl][ki * 32 + quad * 8];
#pragma unroll
                for (int ct = 0; ct < 4; ct++) {
                    short8 vb = *(const short8*)&Vs[cb][ct * 16 + nidx][ki * 32 + quad * 8];
                    oacc[ct] = __builtin_amdgcn_mfma_f32_16x16x32_bf16(pa, vb, oacc[ct], 0, 0, 0);
                }
            }
            __builtin_amdgcn_s_setprio(0);
        }

        // rows owned per-lane; sum over the 4 quads holding the same q-row
        psum += __shfl_xor(psum, 16);
        psum += __shfl_xor(psum, 32);
        const float invl = 1.0f / psum;
        if (quad == 0) ig[qrowg] = invl;   // for the rescale kernel

        // ---- zero strictly-upper tiles (nontemporal stream) ----
        const int zc0 = (qt + 1) * 64;
        if (zc0 < SEQ) {
            const floatx4 zz = (floatx4)0.0f;
            const int zw4 = (SEQ - zc0) >> 2;
            const int total = 64 * zw4;
            for (int i = tid; i < total; i += 256) {
                int r = i / zw4;
                int c = zc0 + (i - r * zw4) * 4;
                __builtin_nontemporal_store(zz, (floatx4*)&ag[(size_t)(qt * 64 + r) * SEQ + c]);
            }
        }

        // ---- ctx epilogue: normalize and store bf16 [B][S][H*D] ----
        // invl for local row (quad*4+rg) lives in lane (quad*4+rg) of this
        // wave (all quads hold the full row sum after the xor-16/32 reduce).
#pragma unroll
        for (int ct = 0; ct < 4; ct++) {
#pragma unroll
            for (int rg = 0; rg < 4; rg++) {
                int rowg = qt * 64 + crow0 + rg;
                int d = ct * 16 + nidx;
                float iv = __shfl(invl, quad * 4 + rg);
                float val = oacc[ct][rg] * iv;
                ctx[((size_t)(b * SEQ + rowg) * NH + h) * HD + d] = f2bf(val);
            }
        }
    }
}

// ---------------------------------------------------------------------------
// Kernel B2: rescale the attn lower triangle by invl (row-constant).  The
// strictly-upper region is exact zeros and needs no touch.  Memory-bound:
// 268 MB read + 268 MB write, NT both ways.  Complementary-pair blocks for
// uniform work.
// ---------------------------------------------------------------------------
__global__ __launch_bounds__(256) void rescale_kernel(
    float* __restrict__ attn, const float* __restrict__ invl_g)
{
    const int h = blockIdx.y;
    const int b = blockIdx.z;
    const int tid  = threadIdx.x;
    const int lane = tid & 63;
    const int wv   = tid >> 6;
    float* ag = attn + (size_t)(b * NH + h) * SEQ * SEQ;
    const float* ig = invl_g + (size_t)(b * NH + h) * SEQ;

    __shared__ float iv[64];

    for (int rep = 0; rep < 2; rep++) {
        const int qt = rep ? (31 - (int)blockIdx.x) : (int)blockIdx.x;
        __syncthreads();                    // protect iv reuse across reps
        if (tid < 64) iv[tid] = ig[qt * 64 + tid];
        __syncthreads();
        const int w4 = 16 * (qt + 1);       // row width in float4 (cols 0..(qt+1)*64)
        // wave wv owns rows wv*16..wv*16+15; lanes stride the row
#pragma unroll 1
        for (int rr = 0; rr < 16; rr++) {
            const int r = wv * 16 + rr;
            const float s = iv[r];
            floatx4* rowp = (floatx4*)(ag + (size_t)(qt * 64 + r) * SEQ);
            for (int c4 = lane; c4 < w4; c4 += 64) {
                floatx4 vv = __builtin_nontemporal_load(rowp + c4);
                vv *= s;                     // zeros above diag inside tile stay 0
                __builtin_nontemporal_store(vv, rowp + c4);
            }
        }
    }
}

// ---------------------------------------------------------------------------
// Kernel C: output projection.  out = ctx(bf16) @ o_w^T + o_b  -> fp32
// ---------------------------------------------------------------------------
__global__ __launch_bounds__(256) void oproj_kernel(
    const unsigned short* __restrict__ ctx,
    const float* __restrict__ ow, const float* __restrict__ ob,
    float* __restrict__ out)
{
    const int n0 = blockIdx.x * 128;
    const int m0 = blockIdx.y * 128;
    const int tid  = threadIdx.x;
    const int lane = tid & 63;
    const int wv   = tid >> 6;
    const int nidx = lane & 15;
    const int quad = lane >> 4;

    __shared__ unsigned short As[128][40];
    __shared__ unsigned short Bs[128][40];

    floatx4 acc[2][8];
#pragma unroll
    for (int rt = 0; rt < 2; rt++)
#pragma unroll
        for (int ct = 0; ct < 8; ct++) acc[rt][ct] = (floatx4)0.0f;

    const int srow = tid >> 1;
    const int scol = (tid & 1) * 16;

    for (int k0 = 0; k0 < HIDN; k0 += 32) {
        __syncthreads();
        {
            const uint4* g = (const uint4*)(ctx + (size_t)(m0 + srow) * HIDN + k0 + scol);
            uint4 u0 = g[0], u1 = g[1];
            *(uint4*)&As[srow][scol]     = u0;
            *(uint4*)&As[srow][scol + 8] = u1;
        }
        {
            const float4* g = (const float4*)(ow + (size_t)(n0 + srow) * HIDN + k0 + scol);
            float4 f0 = g[0], f1 = g[1], f2 = g[2], f3 = g[3];
            *(ushort8*)&Bs[srow][scol]     = pack16(f0, f1);
            *(ushort8*)&Bs[srow][scol + 8] = pack16(f2, f3);
        }
        __syncthreads();

        short8 a[2], bb[8];
#pragma unroll
        for (int rt = 0; rt < 2; rt++)
            a[rt] = *(const short8*)&As[wv * 32 + rt * 16 + nidx][quad * 8];
#pragma unroll
        for (int ct = 0; ct < 8; ct++)
            bb[ct] = *(const short8*)&Bs[ct * 16 + nidx][quad * 8];
#pragma unroll
        for (int rt = 0; rt < 2; rt++)
#pragma unroll
            for (int ct = 0; ct < 8; ct++)
                acc[rt][ct] = __builtin_amdgcn_mfma_f32_16x16x32_bf16(a[rt], bb[ct], acc[rt][ct], 0, 0, 0);
    }

#pragma unroll
    for (int ct = 0; ct < 8; ct++) {
        int col = n0 + ct * 16 + nidx;
        float bcol = ob[col];
#pragma unroll
        for (int rt = 0; rt < 2; rt++) {
#pragma unroll
            for (int rg = 0; rg < 4; rg++) {
                int row = m0 + wv * 32 + rt * 16 + quad * 4 + rg;
                out[(size_t)row * HIDN + col] = acc[rt][ct][rg] + bcol;
            }
        }
    }
}

extern "C" void kernel_launch(void* const* d_in, const int* in_sizes, int n_in,
                              void* d_out, int out_size, void* d_ws, size_t ws_size,
                              hipStream_t stream) {
    const float* x       = (const float*)d_in[0];
    // d_in[1] attention_mask: structurally causal, applied in-kernel (not read)
    const float* scaling = (const float*)d_in[2];
    const float* qw = (const float*)d_in[3];
    const float* qb = (const float*)d_in[4];
    const float* kw = (const float*)d_in[5];
    const float* kb = (const float*)d_in[6];
    const float* vw = (const float*)d_in[7];
    const float* vb = (const float*)d_in[8];
    const float* ow = (const float*)d_in[9];
    const float* ob = (const float*)d_in[10];

    float* out  = (float*)d_out;                          // [B,S,HID] fp32
    float* attn = out + (size_t)BATCH * SEQ * HIDN;       // [B,H,S,S] fp32

    const size_t per = (size_t)BATCH * NH * SEQ * HD;     // 4,194,304 elems
    unsigned short* qbuf = (unsigned short*)d_ws;
    unsigned short* kbuf = qbuf + per;
    unsigned short* vbuf = kbuf + per;
    unsigned short* ctxb = vbuf + per;
    float* invlb = (float*)(ctxb + per);                  // [B,NH,SEQ] fp32

    qkv_kernel<<<dim3(8, 32, 3), 256, 0, stream>>>(
        x, qw, qb, kw, kb, vw, vb, scaling, qbuf, kbuf, vbuf);
    attn_kernel<<<dim3(16, NH, BATCH), 256, 0, stream>>>(
        qbuf, kbuf, vbuf, attn, ctxb, invlb);
    rescale_kernel<<<dim3(16, NH, BATCH), 256, 0, stream>>>(
        attn, invlb);
    oproj_kernel<<<dim3(8, 32), 256, 0, stream>>>(
        ctxb, ow, ob, out);
}

// Round 9
// 786.333 us; speedup vs baseline: 1.2130x; 1.2130x over previous
//
#include <hip/hip_runtime.h>
#include <hip/hip_bf16.h>

#define BATCH 2
#define SEQ   2048
#define HIDN  1024
#define NH    16
#define HD    64

typedef __attribute__((ext_vector_type(8))) short short8;
typedef __attribute__((ext_vector_type(4))) float floatx4;
typedef __attribute__((ext_vector_type(8))) unsigned short ushort8;
typedef __attribute__((ext_vector_type(4))) unsigned short ushort4v;

__device__ __forceinline__ unsigned short f2bf(float f) {
    union { float f; unsigned int u; } v; v.f = f;
    unsigned int u = v.u;
    u += 0x7fffu + ((u >> 16) & 1u);   // round-to-nearest-even
    return (unsigned short)(u >> 16);
}

__device__ __forceinline__ ushort8 pack16(float4 f0, float4 f1) {
    ushort8 r;
    r[0] = f2bf(f0.x); r[1] = f2bf(f0.y); r[2] = f2bf(f0.z); r[3] = f2bf(f0.w);
    r[4] = f2bf(f1.x); r[5] = f2bf(f1.y); r[6] = f2bf(f1.z); r[7] = f2bf(f1.w);
    return r;
}

// ---------------------------------------------------------------------------
// Kernel P: one-shot fp32 -> bf16 conversion of x and the 4 weight matrices.
// Removes the per-tile pack16 VALU work from every GEMM K-step (the packs
// were ~4:1 VALU:MFMA in the projections).  ~50 MB traffic ≈ 10 us.
// Each block converts 2048 elems (256 thr x 8).
// ---------------------------------------------------------------------------
__global__ __launch_bounds__(256) void convert_kernel(
    const float* __restrict__ x,
    const float* __restrict__ qw, const float* __restrict__ kw,
    const float* __restrict__ vw, const float* __restrict__ ow,
    unsigned short* __restrict__ xb,
    unsigned short* __restrict__ wb,    // [3][1024][1024] q,k,v
    unsigned short* __restrict__ owb)
{
    const int bid = blockIdx.x;
    const float* src; unsigned short* dst; size_t base;
    if (bid < 2048)      { src = x;  dst = xb;            base = (size_t)bid * 2048; }
    else if (bid < 2560) { src = qw; dst = wb;            base = (size_t)(bid - 2048) * 2048; }
    else if (bid < 3072) { src = kw; dst = wb + 1048576;  base = (size_t)(bid - 2560) * 2048; }
    else if (bid < 3584) { src = vw; dst = wb + 2097152;  base = (size_t)(bid - 3072) * 2048; }
    else                 { src = ow; dst = owb;           base = (size_t)(bid - 3584) * 2048; }
    const size_t i = base + (size_t)threadIdx.x * 8;
    const float4* g = (const float4*)(src + i);
    *(ushort8*)(dst + i) = pack16(g[0], g[1]);
}

// ---------------------------------------------------------------------------
// Kernel A: fused QKV projection from PRE-CONVERTED bf16 inputs.
// y = xb @ wb[z]^T + b; writes bf16 [B][H][S][D]; q pre-scaled by
// softplus(scaling[d])*LOG2E^2/8 (attn uses exp2: 2^s == e^logit).
// 128x64 tile (grid 16x32x3 = 1536 blocks = 6 blocks/CU; was 3), 4 waves.
// Staging is pure uint4 copies - no conversion in the loop.
// ---------------------------------------------------------------------------
__global__ __launch_bounds__(256) void qkv_kernel(
    const unsigned short* __restrict__ xb,
    const unsigned short* __restrict__ wb,
    const float* __restrict__ qbias, const float* __restrict__ kbias,
    const float* __restrict__ vbias,
    const float* __restrict__ scaling,
    unsigned short* __restrict__ qo,
    unsigned short* __restrict__ ko,
    unsigned short* __restrict__ vo)
{
    const int z = blockIdx.z;
    const unsigned short* w = wb + (size_t)z * HIDN * HIDN;
    const float* bias = (z == 0) ? qbias : (z == 1) ? kbias : vbias;
    unsigned short* dst = (z == 0) ? qo : (z == 1) ? ko : vo;

    const int n0 = blockIdx.x * 64;
    const int m0 = blockIdx.y * 128;
    const int tid  = threadIdx.x;
    const int lane = tid & 63;
    const int wv   = tid >> 6;
    const int nidx = lane & 15;
    const int quad = lane >> 4;

    __shared__ unsigned short As[128][40];  // +8 pad, rows 16B aligned
    __shared__ unsigned short Bs[64][40];

    floatx4 acc[2][4];
#pragma unroll
    for (int rt = 0; rt < 2; rt++)
#pragma unroll
        for (int ct = 0; ct < 4; ct++) acc[rt][ct] = (floatx4)0.0f;

    const int srowA = tid >> 1, scolA = (tid & 1) * 16;   // 16 bf16 each
    const int srowB = tid >> 2, scolB = (tid & 3) * 8;    // 8 bf16 each

    for (int k0 = 0; k0 < HIDN; k0 += 32) {
        __syncthreads();
        {
            const uint4* g = (const uint4*)(xb + (size_t)(m0 + srowA) * HIDN + k0 + scolA);
            *(uint4*)&As[srowA][scolA]     = g[0];
            *(uint4*)&As[srowA][scolA + 8] = g[1];
        }
        {
            const uint4* g = (const uint4*)(w + (size_t)(n0 + srowB) * HIDN + k0 + scolB);
            *(uint4*)&Bs[srowB][scolB] = g[0];
        }
        __syncthreads();

        short8 a[2], bb[4];
#pragma unroll
        for (int rt = 0; rt < 2; rt++)
            a[rt] = *(const short8*)&As[wv * 32 + rt * 16 + nidx][quad * 8];
#pragma unroll
        for (int ct = 0; ct < 4; ct++)
            bb[ct] = *(const short8*)&Bs[ct * 16 + nidx][quad * 8];
#pragma unroll
        for (int rt = 0; rt < 2; rt++)
#pragma unroll
            for (int ct = 0; ct < 4; ct++)
                acc[rt][ct] = __builtin_amdgcn_mfma_f32_16x16x32_bf16(a[rt], bb[ct], acc[rt][ct], 0, 0, 0);
    }

#pragma unroll
    for (int ct = 0; ct < 4; ct++) {
        int col = n0 + ct * 16 + nidx;
        float bcol = bias[col];
        float mult = 1.0f;
        if (z == 0) {
            float sc = scaling[col & (HD - 1)];
            // softplus(sc) * LOG2E^2 / 8  (LOG2E^2 = 2.0813689)
            mult = __logf(1.0f + __expf(sc)) * 0.26017112f;
        }
#pragma unroll
        for (int rt = 0; rt < 2; rt++) {
#pragma unroll
            for (int rg = 0; rg < 4; rg++) {
                int row = m0 + wv * 32 + rt * 16 + quad * 4 + rg;  // C/D: col=lane&15, row=quad*4+reg
                float val = (acc[rt][ct][rg] + bcol) * mult;
                int b_ = row >> 11, s_ = row & (SEQ - 1);
                int h_ = col >> 6,  d_ = col & (HD - 1);
                dst[((size_t)(b_ * NH + h_) * SEQ + s_) * HD + d_] = f2bf(val);
            }
        }
    }
}

// ---------------------------------------------------------------------------
// Kernel B: causal attention, TWO-PASS (measured-good structure).  Each block
// serially processes the complementary q-tile pair {bx, 31-bx} -> uniform
// 33 k-tiles per block.  QK^T operand-swapped: mfma(A=K-subtile, B=Q-rows);
// lane owns 4 consecutive k-cols of one q-row -> float4 attn stores, 8B Ps
// writes, scalar psum.  K/Q direct from global (L2-resident).  Pass 1
// barrier-free (row sums).  Pass 2: V^T staged double-buffered (1 barrier),
// writes NORMALIZED attn (NT), PV MFMA.  e = 2^s (q pre-scaled w/ LOG2E^2).
// ---------------------------------------------------------------------------
__global__ __launch_bounds__(256) void attn_kernel(
    const unsigned short* __restrict__ q,
    const unsigned short* __restrict__ k,
    const unsigned short* __restrict__ v,
    float* __restrict__ attn,
    unsigned short* __restrict__ ctx)
{
    const int h  = blockIdx.y;
    const int b  = blockIdx.z;
    const int tid  = threadIdx.x;
    const int lane = tid & 63;
    const int wv   = tid >> 6;
    const int nidx = lane & 15;
    const int quad = lane >> 4;

    const unsigned short* qg = q + (size_t)((b * NH + h) * SEQ) * HD;
    const unsigned short* kg = k + (size_t)((b * NH + h) * SEQ) * HD;
    const unsigned short* vg = v + (size_t)((b * NH + h) * SEQ) * HD;
    float* ag = attn + (size_t)(b * NH + h) * SEQ * SEQ;

    __shared__ unsigned short Vs[2][64][72];   // V^T double buffer: [d][key]
    __shared__ unsigned short Ps[64][72];

    const int srow = tid >> 2;   // 0..63
    const int sseg = tid & 3;    // 0..3
    const int qrowl = wv * 16 + nidx;          // this lane's q-row (local)
    const int crow0 = wv * 16 + quad * 4;      // PV C-frag first row (local)

    for (int rep = 0; rep < 2; rep++) {
        const int qt = rep ? (31 - (int)blockIdx.x) : (int)blockIdx.x;
        __syncthreads();   // rep>0: previous rep's PV reads of Vs done

        // Q rows: loop-invariant B-operand of swapped QK^T, direct from global
        const unsigned short* qrow = qg + (size_t)(qt * 64 + qrowl) * HD;
        const short8 qb0 = *(const short8*)(qrow + quad * 8);
        const short8 qb1 = *(const short8*)(qrow + 32 + quad * 8);
        const int qrowg = qt * 64 + qrowl;     // global q-row

        // ---- pass 1: row sums of exp2(scores); no LDS, no barriers ----
        float psum = 0.0f;
        for (int kt = 0; kt <= qt; kt++) {
            const unsigned short* kbase = kg + (size_t)(kt * 64) * HD;
            const bool diag = (kt == qt);
#pragma unroll
            for (int ct = 0; ct < 4; ct++) {
                const unsigned short* krow = kbase + (ct * 16 + nidx) * HD;
                short8 ak0 = *(const short8*)(krow + quad * 8);
                short8 ak1 = *(const short8*)(krow + 32 + quad * 8);
                floatx4 sacc = (floatx4)0.0f;
                __builtin_amdgcn_s_setprio(1);
                sacc = __builtin_amdgcn_mfma_f32_16x16x32_bf16(ak0, qb0, sacc, 0, 0, 0);
                sacc = __builtin_amdgcn_mfma_f32_16x16x32_bf16(ak1, qb1, sacc, 0, 0, 0);
                __builtin_amdgcn_s_setprio(0);
                const int kcol0 = kt * 64 + ct * 16 + quad * 4;
#pragma unroll
                for (int rg = 0; rg < 4; rg++) {
                    float e = exp2f(sacc[rg]);   // == e^logit (prescale has LOG2E^2)
                    if (diag && kcol0 + rg > qrowg) e = 0.0f;
                    psum += e;
                }
            }
        }

        // rows owned per-lane; sum over the 4 quads holding the same q-row
        psum += __shfl_xor(psum, 16);
        psum += __shfl_xor(psum, 32);
        const float invl = 1.0f / psum;

        // ---- pass 2: write normalized attn, accumulate PV ----
        floatx4 oacc[4];
#pragma unroll
        for (int ct = 0; ct < 4; ct++) oacc[ct] = (floatx4)0.0f;

        {   // prologue: stage V^T tile 0 into buffer 0
            const uint4* g = (const uint4*)(vg + (size_t)(srow) * HD);
            uint4 u0 = g[sseg], u1 = g[sseg + 4];
            union { uint4 u; unsigned short s[8]; } w0, w1;
            w0.u = u0; w1.u = u1;
#pragma unroll
            for (int j = 0; j < 8; j++) Vs[0][sseg * 8 + j][srow]      = w0.s[j];
#pragma unroll
            for (int j = 0; j < 8; j++) Vs[0][sseg * 8 + 32 + j][srow] = w1.s[j];
        }

        for (int kt = 0; kt <= qt; kt++) {
            __syncthreads();   // staging of Vs[kt&1] (prev iter / prologue) visible
            // prefetch-stage next V tile into the other buffer (overlaps compute)
            if (kt < qt) {
                const uint4* g = (const uint4*)(vg + (size_t)((kt + 1) * 64 + srow) * HD);
                uint4 u0 = g[sseg], u1 = g[sseg + 4];
                union { uint4 u; unsigned short s[8]; } w0, w1;
                w0.u = u0; w1.u = u1;
                const int nb = (kt + 1) & 1;
#pragma unroll
                for (int j = 0; j < 8; j++) Vs[nb][sseg * 8 + j][srow]      = w0.s[j];
#pragma unroll
                for (int j = 0; j < 8; j++) Vs[nb][sseg * 8 + 32 + j][srow] = w1.s[j];
            }

            const unsigned short* kbase = kg + (size_t)(kt * 64) * HD;
            const bool diag = (kt == qt);
            const int cb = kt & 1;
#pragma unroll
            for (int ct = 0; ct < 4; ct++) {
                const unsigned short* krow = kbase + (ct * 16 + nidx) * HD;
                short8 ak0 = *(const short8*)(krow + quad * 8);
                short8 ak1 = *(const short8*)(krow + 32 + quad * 8);
                floatx4 sacc = (floatx4)0.0f;
                __builtin_amdgcn_s_setprio(1);
                sacc = __builtin_amdgcn_mfma_f32_16x16x32_bf16(ak0, qb0, sacc, 0, 0, 0);
                sacc = __builtin_amdgcn_mfma_f32_16x16x32_bf16(ak1, qb1, sacc, 0, 0, 0);
                __builtin_amdgcn_s_setprio(0);
                const int kcol0 = kt * 64 + ct * 16 + quad * 4;
                floatx4 av;
                ushort4v pb;
#pragma unroll
                for (int rg = 0; rg < 4; rg++) {
                    float e = exp2f(sacc[rg]);
                    if (diag && kcol0 + rg > qrowg) e = 0.0f;
                    av[rg] = e * invl;
                    pb[rg] = f2bf(e);       // unnormalized P for PV
                }
                __builtin_nontemporal_store(av, (floatx4*)&ag[(size_t)qrowg * SEQ + kcol0]);
                *(ushort4v*)&Ps[qrowl][ct * 16 + quad * 4] = pb;      // 8B ds_write
            }
            // No barrier: Ps rows [wv*16, wv*16+16) are written and read by
            // the SAME wave; compiler inserts the lgkmcnt wait.

            // PV: ctx[q][d] += P~[q][key] * V[key][d]
            __builtin_amdgcn_s_setprio(1);
#pragma unroll
            for (int ki = 0; ki < 2; ki++) {
                short8 pa = *(const short8*)&Ps[qrowl][ki * 32 + quad * 8];
#pragma unroll
                for (int ct = 0; ct < 4; ct++) {
                    short8 vb = *(const short8*)&Vs[cb][ct * 16 + nidx][ki * 32 + quad * 8];
                    oacc[ct] = __builtin_amdgcn_mfma_f32_16x16x32_bf16(pa, vb, oacc[ct], 0, 0, 0);
                }
            }
            __builtin_amdgcn_s_setprio(0);
        }

        // ---- zero strictly-upper tiles (nontemporal stream) ----
        const int zc0 = (qt + 1) * 64;
        if (zc0 < SEQ) {
            const floatx4 zz = (floatx4)0.0f;
            const int zw4 = (SEQ - zc0) >> 2;
            const int total = 64 * zw4;
            for (int i = tid; i < total; i += 256) {
                int r = i / zw4;
                int c = zc0 + (i - r * zw4) * 4;
                __builtin_nontemporal_store(zz, (floatx4*)&ag[(size_t)(qt * 64 + r) * SEQ + c]);
            }
        }

        // ---- ctx epilogue: normalize and store bf16 [B][S][H*D] ----
        // invl for local row (quad*4+rg) lives in lane (quad*4+rg) of this
        // wave (all quads hold the full row sum after the xor-16/32 reduce).
#pragma unroll
        for (int ct = 0; ct < 4; ct++) {
#pragma unroll
            for (int rg = 0; rg < 4; rg++) {
                int rowg = qt * 64 + crow0 + rg;
                int d = ct * 16 + nidx;
                float iv = __shfl(invl, quad * 4 + rg);
                float val = oacc[ct][rg] * iv;
                ctx[((size_t)(b * SEQ + rowg) * NH + h) * HD + d] = f2bf(val);
            }
        }
    }
}

// ---------------------------------------------------------------------------
// Kernel C: output projection.  out = ctx(bf16) @ owb(bf16)^T + o_b -> fp32.
// 64x64 tile (grid 16x64 = 1024 blocks = 4 blocks/CU; was 1 block/CU at
// 128x128 -> zero latency hiding).  Pure-copy staging.
// ---------------------------------------------------------------------------
__global__ __launch_bounds__(256) void oproj_kernel(
    const unsigned short* __restrict__ ctx,
    const unsigned short* __restrict__ owb, const float* __restrict__ ob,
    float* __restrict__ out)
{
    const int n0 = blockIdx.x * 64;
    const int m0 = blockIdx.y * 64;
    const int tid  = threadIdx.x;
    const int lane = tid & 63;
    const int wv   = tid >> 6;
    const int nidx = lane & 15;
    const int quad = lane >> 4;

    __shared__ unsigned short As[64][40];
    __shared__ unsigned short Bs[64][40];

    floatx4 acc[4];
#pragma unroll
    for (int ct = 0; ct < 4; ct++) acc[ct] = (floatx4)0.0f;

    const int srow = tid >> 2, scol = (tid & 3) * 8;   // 8 bf16 each

    for (int k0 = 0; k0 < HIDN; k0 += 32) {
        __syncthreads();
        {
            const uint4* g = (const uint4*)(ctx + (size_t)(m0 + srow) * HIDN + k0 + scol);
            *(uint4*)&As[srow][scol] = g[0];
        }
        {
            const uint4* g = (const uint4*)(owb + (size_t)(n0 + srow) * HIDN + k0 + scol);
            *(uint4*)&Bs[srow][scol] = g[0];
        }
        __syncthreads();

        short8 a = *(const short8*)&As[wv * 16 + nidx][quad * 8];
        short8 bb[4];
#pragma unroll
        for (int ct = 0; ct < 4; ct++)
            bb[ct] = *(const short8*)&Bs[ct * 16 + nidx][quad * 8];
#pragma unroll
        for (int ct = 0; ct < 4; ct++)
            acc[ct] = __builtin_amdgcn_mfma_f32_16x16x32_bf16(a, bb[ct], acc[ct], 0, 0, 0);
    }

#pragma unroll
    for (int ct = 0; ct < 4; ct++) {
        int col = n0 + ct * 16 + nidx;
        float bcol = ob[col];
#pragma unroll
        for (int rg = 0; rg < 4; rg++) {
            int row = m0 + wv * 16 + quad * 4 + rg;
            out[(size_t)row * HIDN + col] = acc[ct][rg] + bcol;
        }
    }
}

extern "C" void kernel_launch(void* const* d_in, const int* in_sizes, int n_in,
                              void* d_out, int out_size, void* d_ws, size_t ws_size,
                              hipStream_t stream) {
    const float* x       = (const float*)d_in[0];
    // d_in[1] attention_mask: structurally causal, applied in-kernel (not read)
    const float* scaling = (const float*)d_in[2];
    const float* qw = (const float*)d_in[3];
    const float* qb = (const float*)d_in[4];
    const float* kw = (const float*)d_in[5];
    const float* kb = (const float*)d_in[6];
    const float* vw = (const float*)d_in[7];
    const float* vb = (const float*)d_in[8];
    const float* ow = (const float*)d_in[9];
    const float* ob = (const float*)d_in[10];

    float* out  = (float*)d_out;                          // [B,S,HID] fp32
    float* attn = out + (size_t)BATCH * SEQ * HIDN;       // [B,H,S,S] fp32

    const size_t per = (size_t)BATCH * NH * SEQ * HD;     // 4,194,304 elems
    unsigned short* qbuf = (unsigned short*)d_ws;
    unsigned short* kbuf = qbuf + per;
    unsigned short* vbuf = kbuf + per;
    unsigned short* ctxb = vbuf + per;
    unsigned short* xb   = ctxb + per;                    // [B*S][HIDN] bf16
    unsigned short* wbb  = xb + per;                      // [3][1024][1024] bf16
    unsigned short* owb  = wbb + (size_t)3 * HIDN * HIDN; // [1024][1024] bf16

    convert_kernel<<<dim3(4096), 256, 0, stream>>>(
        x, qw, kw, vw, ow, xb, wbb, owb);
    qkv_kernel<<<dim3(16, 32, 3), 256, 0, stream>>>(
        xb, wbb, qb, kb, vb, scaling, qbuf, kbuf, vbuf);
    attn_kernel<<<dim3(16, NH, BATCH), 256, 0, stream>>>(
        qbuf, kbuf, vbuf, attn, ctxb);
    oproj_kernel<<<dim3(16, 64), 256, 0, stream>>>(
        ctxb, owb, ob, out);
}